// Round 1
// baseline (1233.540 us; speedup 1.0000x reference)
//
#include <hip/hip_runtime.h>

#define L 10

using bf16x8 = __attribute__((ext_vector_type(8))) __bf16;
using u16x8  = __attribute__((ext_vector_type(8))) unsigned short;
using f32x4  = __attribute__((ext_vector_type(4))) float;

__device__ __forceinline__ unsigned short f2bf(float f) {
  unsigned int u = __float_as_uint(f);
  u += 0x7FFFu + ((u >> 16) & 1u);          // RNE
  return (unsigned short)(u >> 16);
}
__device__ __forceinline__ float bf2f(unsigned short h) {
  return __uint_as_float(((unsigned int)h) << 16);
}

// ---------------------------------------------------------------------------
// Plaquette: single thread, exact fp32, matching JAX trunc-cast + python mod.
// ---------------------------------------------------------------------------
__global__ void plaq_kernel(const float* __restrict__ x,
                            const float* __restrict__ field,
                            float* __restrict__ out) {
  if (threadIdx.x != 0 || blockIdx.x != 0) return;
  int c[4];
#pragma unroll
  for (int i = 0; i < 4; ++i) {
    int v = (int)x[i];          // trunc toward zero == jnp astype(int32)
    v %= L; if (v < 0) v += L;  // python-style mod
    c[i] = v;
  }
  float S = 0.f;
  for (int mu = 0; mu < 4; ++mu)
    for (int nu = mu + 1; nu < 4; ++nu) {
      int p[4] = {c[0], c[1], c[2], c[3]};
      float l1 = field[((p[0]*L + p[1])*L + p[2])*4 + mu];
      p[mu] = (p[mu] + 1) % L;
      float l2 = field[((p[0]*L + p[1])*L + p[2])*4 + nu];
      p[nu] = (p[nu] + 1) % L;
      float l3 = field[((p[0]*L + p[1])*L + p[2])*4 + mu];
      float l4 = field[((c[0]*L + c[1])*L + c[2])*4 + nu];
      S += l1 + l2 - l3 - l4;
    }
  out[0] = expf(S);
}

// ---------------------------------------------------------------------------
// fc1: h = relu(x[16384,4] @ fw1[4,2048] + fb1) -> bf16. One thread = 8 cols.
// ---------------------------------------------------------------------------
__global__ void fc1_kernel(const float* __restrict__ x,
                           const float* __restrict__ fw1,
                           const float* __restrict__ fb1,
                           unsigned short* __restrict__ h) {
  const int N = 2048;
  int idx = blockIdx.x * blockDim.x + threadIdx.x;   // M * 256 threads
  int m  = idx >> 8;
  int n0 = (idx & 255) * 8;
  float4 xv = *(const float4*)(x + (size_t)m * 4);
  unsigned short o[8];
#pragma unroll
  for (int j = 0; j < 8; ++j) {
    int n = n0 + j;
    float s = fb1[n] + xv.x * fw1[n] + xv.y * fw1[N + n]
                     + xv.z * fw1[2*N + n] + xv.w * fw1[3*N + n];
    o[j] = f2bf(fmaxf(s, 0.f));
  }
  *(u16x8*)(h + (size_t)m * N + n0) = *(const u16x8*)o;
}

// ---------------------------------------------------------------------------
// Weight transpose+convert: W[K][N] f32 -> WT[N][K] bf16. LDS 32x33 tile.
// ---------------------------------------------------------------------------
__global__ void transpose_bf16_kernel(const float* __restrict__ W,
                                      unsigned short* __restrict__ WT,
                                      int K, int N) {
  __shared__ float tile[32][33];
  int n0 = blockIdx.x * 32, k0 = blockIdx.y * 32;
  int tx = threadIdx.x, ty = threadIdx.y;   // 32 x 8
#pragma unroll
  for (int i = 0; i < 32; i += 8)
    tile[ty + i][tx] = W[(size_t)(k0 + ty + i) * N + n0 + tx];
  __syncthreads();
#pragma unroll
  for (int i = 0; i < 32; i += 8)
    WT[(size_t)(n0 + ty + i) * K + k0 + tx] = f2bf(tile[tx][ty + i]);
}

// ---------------------------------------------------------------------------
// bf16 MFMA GEMM: C[M,N] = act(A[M,K] @ BT[N,K]^T + bias)
// 128x128 tile, BK=64, 4 waves (2x2), 4x4 frags of 16x16x32, global_load_lds.
// ---------------------------------------------------------------------------
template<int RELU, int SF32, int SBF16>
__global__ __launch_bounds__(256, 2)
void gemm_kernel(const unsigned short* __restrict__ A,
                 const unsigned short* __restrict__ BT,
                 const float* __restrict__ bias,
                 float* __restrict__ outF,
                 unsigned short* __restrict__ outB,
                 int N, int K) {
  constexpr int BM = 128, BN = 128, BK = 64;
  __shared__ unsigned short As[BM * BK];
  __shared__ unsigned short Bs[BN * BK];

  const int bm = blockIdx.x, bn = blockIdx.y;
  const int tid = threadIdx.x;
  const int wid = tid >> 6, lane = tid & 63;
  const int wr = wid >> 1, wc = wid & 1;
  const int lr = lane & 15, lg = lane >> 4;

  f32x4 acc[4][4];
#pragma unroll
  for (int m = 0; m < 4; ++m)
#pragma unroll
    for (int n = 0; n < 4; ++n) acc[m][n] = (f32x4)0.f;

  // staging: wave w owns rows [w*32, w*32+32) of the tile.
  // inst i (0..3): LDS base = w*4096B + i*1024B; lane l -> +l*16B
  // -> row = w*32 + i*8 + l/8, col elems = (l%8)*8
  const int srow = wid * 32 + (lane >> 3);
  const int scol = (lane & 7) * 8;
  const unsigned short* Ag = A  + (size_t)(bm * BM + srow) * K + scol;
  const unsigned short* Bg = BT + (size_t)(bn * BN + srow) * K + scol;

  for (int kt = 0; kt < K; kt += BK) {
#pragma unroll
    for (int i = 0; i < 4; ++i) {
      __builtin_amdgcn_global_load_lds(
          (const __attribute__((address_space(1))) unsigned int*)(Ag + (size_t)i * 8 * K + kt),
          (__attribute__((address_space(3))) unsigned int*)&As[wid * 2048 + i * 512],
          16, 0, 0);
      __builtin_amdgcn_global_load_lds(
          (const __attribute__((address_space(1))) unsigned int*)(Bg + (size_t)i * 8 * K + kt),
          (__attribute__((address_space(3))) unsigned int*)&Bs[wid * 2048 + i * 512],
          16, 0, 0);
    }
    __syncthreads();   // compiler drains vmcnt before s_barrier

#pragma unroll
    for (int kk = 0; kk < 2; ++kk) {
      u16x8 af[4], bf[4];
#pragma unroll
      for (int m = 0; m < 4; ++m)
        af[m] = *(const u16x8*)&As[(wr * 64 + m * 16 + lr) * BK + kk * 32 + lg * 8];
#pragma unroll
      for (int n = 0; n < 4; ++n)
        bf[n] = *(const u16x8*)&Bs[(wc * 64 + n * 16 + lr) * BK + kk * 32 + lg * 8];
#pragma unroll
      for (int m = 0; m < 4; ++m)
#pragma unroll
        for (int n = 0; n < 4; ++n)
          acc[m][n] = __builtin_amdgcn_mfma_f32_16x16x32_bf16(
              __builtin_bit_cast(bf16x8, af[m]),
              __builtin_bit_cast(bf16x8, bf[n]),
              acc[m][n], 0, 0, 0);
    }
    __syncthreads();
  }

  // epilogue: D row = (lane>>4)*4 + r, col = lane&15  (m89-verified layout)
  const int rowBase = bm * BM + wr * 64 + lg * 4;
  const int colBase = bn * BN + wc * 64 + lr;
#pragma unroll
  for (int n = 0; n < 4; ++n) {
    int col = colBase + n * 16;
    float bv = bias[col];
#pragma unroll
    for (int m = 0; m < 4; ++m) {
      int row = rowBase + m * 16;
#pragma unroll
      for (int r = 0; r < 4; ++r) {
        float v = acc[m][n][r] + bv;
        if (RELU) v = fmaxf(v, 0.f);
        size_t o = (size_t)(row + r) * N + col;
        if (SF32)  outF[o] = v;
        if (SBF16) outB[o] = f2bf(v);
      }
    }
  }
}

// ---------------------------------------------------------------------------
// GEMV head: out[m] = sum_k A[m,k]*w[k] + b.  One wave per row.
// ---------------------------------------------------------------------------
__global__ void gemv_kernel(const unsigned short* __restrict__ Abf,
                            const float* __restrict__ wvec,
                            const float* __restrict__ bias,
                            float* __restrict__ out, int K) {
  int row  = blockIdx.x * 4 + (threadIdx.x >> 6);
  int lane = threadIdx.x & 63;
  const unsigned short* ap = Abf + (size_t)row * K;
  float s = 0.f;
  for (int k = lane * 8; k < K; k += 512) {
    u16x8 v = *(const u16x8*)(ap + k);
#pragma unroll
    for (int j = 0; j < 8; ++j) s += bf2f(v[j]) * wvec[k + j];
  }
#pragma unroll
  for (int off = 32; off; off >>= 1) s += __shfl_down(s, off);
  if (lane == 0) out[row] = s + bias[0];
}

// ---------------------------------------------------------------------------
extern "C" void kernel_launch(void* const* d_in, const int* in_sizes, int n_in,
                              void* d_out, int out_size, void* d_ws, size_t ws_size,
                              hipStream_t stream) {
  const float* x     = (const float*)d_in[0];
  const float* field = (const float*)d_in[1];
  const float* fw1   = (const float*)d_in[2];
  const float* fb1   = (const float*)d_in[3];
  const float* fw2   = (const float*)d_in[4];
  const float* fb2   = (const float*)d_in[5];
  const float* ww1   = (const float*)d_in[6];
  const float* wb1   = (const float*)d_in[7];
  const float* ww2   = (const float*)d_in[8];
  const float* wb2   = (const float*)d_in[9];
  const float* ww3   = (const float*)d_in[10];
  const float* wb3   = (const float*)d_in[11];
  const float* tw1   = (const float*)d_in[12];
  const float* tb1   = (const float*)d_in[13];
  const float* tw2   = (const float*)d_in[14];
  const float* tb2   = (const float*)d_in[15];

  const int M = 16384;
  float* outF    = (float*)d_out;                  // field_output [16384,4096]
  float* outWil  = outF + (size_t)M * 4096;        // wilson [16384]
  float* outTop  = outWil + M;                     // topology [16384]
  float* outPlaq = outTop + M;                     // plaq [1]

  char* ws = (char*)d_ws;
  unsigned short* hbuf  = (unsigned short*)(ws);                // h, later w2 (64MB)
  unsigned short* fobuf = (unsigned short*)(ws + 67108864);     // field_output bf16 (128MB)
  unsigned short* cbuf  = (unsigned short*)(ws + 201326592);    // w1, later t (64MB)
  unsigned short* wslot = (unsigned short*)(ws + 268435456);    // rotating WT slot (16MB)
  unsigned short* w2buf = hbuf;

  // plaquette (scalar)
  hipLaunchKernelGGL(plaq_kernel, dim3(1), dim3(64), 0, stream, x, field, outPlaq);

  // h = relu(x @ fw1 + fb1) -> bf16
  hipLaunchKernelGGL(fc1_kernel, dim3(16384), dim3(256), 0, stream, x, fw1, fb1, hbuf);

  // field_output = h @ fw2 + fb2  (f32 -> d_out, bf16 -> ws)
  hipLaunchKernelGGL(transpose_bf16_kernel, dim3(128, 64), dim3(32, 8), 0, stream,
                     fw2, wslot, 2048, 4096);
  hipLaunchKernelGGL((gemm_kernel<0, 1, 1>), dim3(128, 32), dim3(256), 0, stream,
                     hbuf, wslot, fb2, outF, fobuf, 4096, 2048);

  // w1 = relu(fo @ ww1 + wb1)
  hipLaunchKernelGGL(transpose_bf16_kernel, dim3(64, 128), dim3(32, 8), 0, stream,
                     ww1, wslot, 4096, 2048);
  hipLaunchKernelGGL((gemm_kernel<1, 0, 1>), dim3(128, 16), dim3(256), 0, stream,
                     fobuf, wslot, wb1, (float*)nullptr, cbuf, 2048, 4096);

  // w2 = relu(w1 @ ww2 + wb2)
  hipLaunchKernelGGL(transpose_bf16_kernel, dim3(32, 64), dim3(32, 8), 0, stream,
                     ww2, wslot, 2048, 1024);
  hipLaunchKernelGGL((gemm_kernel<1, 0, 1>), dim3(128, 8), dim3(256), 0, stream,
                     cbuf, wslot, wb2, (float*)nullptr, w2buf, 1024, 2048);

  // wilson_output = w2 @ ww3 + wb3
  hipLaunchKernelGGL(gemv_kernel, dim3(4096), dim3(256), 0, stream,
                     w2buf, ww3, wb3, outWil, 1024);

  // t = relu(fo @ tw1 + tb1)
  hipLaunchKernelGGL(transpose_bf16_kernel, dim3(64, 128), dim3(32, 8), 0, stream,
                     tw1, wslot, 4096, 2048);
  hipLaunchKernelGGL((gemm_kernel<1, 0, 1>), dim3(128, 16), dim3(256), 0, stream,
                     fobuf, wslot, tb1, (float*)nullptr, cbuf, 2048, 4096);

  // topology_output = t @ tw2 + tb2
  hipLaunchKernelGGL(gemv_kernel, dim3(4096), dim3(256), 0, stream,
                     cbuf, tw2, tb2, outTop, 2048);

  (void)in_sizes; (void)n_in; (void)out_size; (void)ws_size;
}

// Round 2
// 1095.970 us; speedup vs baseline: 1.1255x; 1.1255x over previous
//
#include <hip/hip_runtime.h>

#define L 10

using bf16x8 = __attribute__((ext_vector_type(8))) __bf16;
using u16x8  = __attribute__((ext_vector_type(8))) unsigned short;
using f32x4  = __attribute__((ext_vector_type(4))) float;

__device__ __forceinline__ unsigned short f2bf(float f) {
  unsigned int u = __float_as_uint(f);
  u += 0x7FFFu + ((u >> 16) & 1u);          // RNE
  return (unsigned short)(u >> 16);
}
__device__ __forceinline__ float bf2f(unsigned short h) {
  return __uint_as_float(((unsigned int)h) << 16);
}

// ---------------------------------------------------------------------------
// Plaquette: single thread, exact fp32, matching JAX trunc-cast + python mod.
// ---------------------------------------------------------------------------
__global__ void plaq_kernel(const float* __restrict__ x,
                            const float* __restrict__ field,
                            float* __restrict__ out) {
  if (threadIdx.x != 0 || blockIdx.x != 0) return;
  int c[4];
#pragma unroll
  for (int i = 0; i < 4; ++i) {
    int v = (int)x[i];
    v %= L; if (v < 0) v += L;
    c[i] = v;
  }
  float S = 0.f;
  for (int mu = 0; mu < 4; ++mu)
    for (int nu = mu + 1; nu < 4; ++nu) {
      int p[4] = {c[0], c[1], c[2], c[3]};
      float l1 = field[((p[0]*L + p[1])*L + p[2])*4 + mu];
      p[mu] = (p[mu] + 1) % L;
      float l2 = field[((p[0]*L + p[1])*L + p[2])*4 + nu];
      p[nu] = (p[nu] + 1) % L;
      float l3 = field[((p[0]*L + p[1])*L + p[2])*4 + mu];
      float l4 = field[((c[0]*L + c[1])*L + c[2])*4 + nu];
      S += l1 + l2 - l3 - l4;
    }
  out[0] = expf(S);
}

// ---------------------------------------------------------------------------
// fc1: h = relu(x[16384,4] @ fw1[4,2048] + fb1) -> bf16.
// ---------------------------------------------------------------------------
__global__ void fc1_kernel(const float* __restrict__ x,
                           const float* __restrict__ fw1,
                           const float* __restrict__ fb1,
                           unsigned short* __restrict__ h) {
  const int N = 2048;
  int idx = blockIdx.x * blockDim.x + threadIdx.x;
  int m  = idx >> 8;
  int n0 = (idx & 255) * 8;
  float4 xv = *(const float4*)(x + (size_t)m * 4);
  unsigned short o[8];
#pragma unroll
  for (int j = 0; j < 8; ++j) {
    int n = n0 + j;
    float s = fb1[n] + xv.x * fw1[n] + xv.y * fw1[N + n]
                     + xv.z * fw1[2*N + n] + xv.w * fw1[3*N + n];
    o[j] = f2bf(fmaxf(s, 0.f));
  }
  *(u16x8*)(h + (size_t)m * N + n0) = *(const u16x8*)o;
}

// ---------------------------------------------------------------------------
// Weight transpose+convert: W[K][N] f32 -> WT[N][K] bf16.
// ---------------------------------------------------------------------------
__global__ void transpose_bf16_kernel(const float* __restrict__ W,
                                      unsigned short* __restrict__ WT,
                                      int K, int N) {
  __shared__ float tile[32][33];
  int n0 = blockIdx.x * 32, k0 = blockIdx.y * 32;
  int tx = threadIdx.x, ty = threadIdx.y;   // 32 x 8
#pragma unroll
  for (int i = 0; i < 32; i += 8)
    tile[ty + i][tx] = W[(size_t)(k0 + ty + i) * N + n0 + tx];
  __syncthreads();
#pragma unroll
  for (int i = 0; i < 32; i += 8)
    WT[(size_t)(n0 + ty + i) * K + k0 + tx] = f2bf(tile[tx][ty + i]);
}

// ---------------------------------------------------------------------------
// 256x256 bf16 MFMA GEMM, BK=32, 4-slot LDS ring (128KB), 8 waves (2Mx4N).
// Counted-vmcnt pipeline (T3/T4), XOR chunk swizzle (T2), setprio (T5),
// bijective XCD blockIdx swizzle (T1).  C = act(A[M,K] @ BT[N,K]^T + bias).
// ---------------------------------------------------------------------------
#define GLL(gp, lp)                                                            \
  __builtin_amdgcn_global_load_lds(                                            \
      (const __attribute__((address_space(1))) unsigned int*)(gp),             \
      (__attribute__((address_space(3))) unsigned int*)(lp), 16, 0, 0)

extern __shared__ char lds_raw[];

template<int RELU, int SF32, int SBF16>
__global__ __launch_bounds__(512)
void gemm256_kernel(const unsigned short* __restrict__ A,
                    const unsigned short* __restrict__ BT,
                    const float* __restrict__ bias,
                    float* __restrict__ outF,
                    unsigned short* __restrict__ outB,
                    int N, int K, int gmx) {
  const int NT = K >> 5;                      // K-tiles of 32 (NT >= 64 here)
  const size_t K128 = (size_t)128 * K;

  // T1: bijective XCD swizzle, bm fastest
  const int nwg = gridDim.x;
  const int q = nwg >> 3, r = nwg & 7;
  const int xcd = blockIdx.x & 7, lid = blockIdx.x >> 3;
  const int wg2 = (xcd < r ? xcd * (q + 1) : r * (q + 1) + (xcd - r) * q) + lid;
  const int bm = wg2 % gmx, bn = wg2 / gmx;

  const int tid  = threadIdx.x;
  const int wid  = tid >> 6, lane = tid & 63;
  const int wr   = wid >> 2, wc = wid & 3;          // 2 x 4 waves
  const int lr   = lane & 15, lg = lane >> 4;

  // ---- staging source (pre-swizzled global address, linear LDS dest) ----
  // LDS byte b (16KB half) -> row = b>>6, chunk = (b>>4)&3; src chunk ^= (row>>1)&3
  const int srow = tid >> 2;                          // 0..127 (round i adds 128)
  const int scol = ((tid & 3) ^ ((tid >> 3) & 3)) * 8;
  const unsigned short* agp = A  + (size_t)(bm * 256 + srow) * K + scol;
  const unsigned short* bgp = BT + (size_t)(bn * 256 + srow) * K + scol;

  // ---- read-side swizzled fragment offsets ----
  const int chunk = lg ^ ((lr >> 1) & 3);
  const int aoff  = (wr * 128 + lr) * 64 + chunk * 16;          // + m*1024
  const int boff  = 16384 + (wc * 64 + lr) * 64 + chunk * 16;   // + n*1024

  f32x4 acc[8][4];
#pragma unroll
  for (int m = 0; m < 8; ++m)
#pragma unroll
    for (int n = 0; n < 4; ++n) acc[m][n] = (f32x4)0.f;

#define STAGE(tt) do {                                                         \
    char* sb = lds_raw + (((tt) & 3) << 15) + (wid << 10);                     \
    const unsigned short* ag = agp + (size_t)(tt) * 32;                        \
    const unsigned short* bg = bgp + (size_t)(tt) * 32;                        \
    GLL(ag,         sb);                                                       \
    GLL(ag + K128,  sb + 8192);                                                \
    GLL(bg,         sb + 16384);                                               \
    GLL(bg + K128,  sb + 24576);                                               \
  } while (0)

  // prologue: tiles 0,1,2 in flight (12 loads)
  STAGE(0); STAGE(1); STAGE(2);

  for (int t = 0; t < NT; ++t) {
    if (t + 3 < NT) STAGE(t + 3);
    const int rem = NT - 1 - t;
    if (rem >= 3)      asm volatile("s_waitcnt vmcnt(12)" ::: "memory");
    else if (rem == 2) asm volatile("s_waitcnt vmcnt(8)"  ::: "memory");
    else if (rem == 1) asm volatile("s_waitcnt vmcnt(4)"  ::: "memory");
    else               asm volatile("s_waitcnt vmcnt(0)"  ::: "memory");
    __builtin_amdgcn_s_barrier();
    asm volatile("" ::: "memory");

    const char* sa = lds_raw + ((t & 3) << 15);
    u16x8 af[8], bfr[4];
#pragma unroll
    for (int m = 0; m < 8; ++m)
      af[m] = *(const u16x8*)(sa + aoff + m * 1024);
#pragma unroll
    for (int n = 0; n < 4; ++n)
      bfr[n] = *(const u16x8*)(sa + boff + n * 1024);

    __builtin_amdgcn_s_setprio(1);
#pragma unroll
    for (int m = 0; m < 8; ++m)
#pragma unroll
      for (int n = 0; n < 4; ++n)
        acc[m][n] = __builtin_amdgcn_mfma_f32_16x16x32_bf16(
            __builtin_bit_cast(bf16x8, af[m]),
            __builtin_bit_cast(bf16x8, bfr[n]),
            acc[m][n], 0, 0, 0);
    __builtin_amdgcn_s_setprio(0);
    __builtin_amdgcn_sched_barrier(0);
    asm volatile("" ::: "memory");
    __builtin_amdgcn_s_barrier();
  }
#undef STAGE

  // epilogue: D row = lg*4 + j (within m*16), col = lr (within n*16)
  const int rowBase = bm * 256 + wr * 128 + lg * 4;
  const int colBase = bn * 256 + wc * 64 + lr;
#pragma unroll
  for (int n = 0; n < 4; ++n) {
    int col = colBase + n * 16;
    float bv = bias[col];
#pragma unroll
    for (int m = 0; m < 8; ++m) {
      int row = rowBase + m * 16;
#pragma unroll
      for (int j = 0; j < 4; ++j) {
        float v = acc[m][n][j] + bv;
        if (RELU) v = fmaxf(v, 0.f);
        size_t o = (size_t)(row + j) * N + col;
        if (SF32)  outF[o] = v;
        if (SBF16) outB[o] = f2bf(v);
      }
    }
  }
}

// ---------------------------------------------------------------------------
// GEMV head: out[m] = sum_k A[m,k]*w[k] + b.  One wave per row.
// ---------------------------------------------------------------------------
__global__ void gemv_kernel(const unsigned short* __restrict__ Abf,
                            const float* __restrict__ wvec,
                            const float* __restrict__ bias,
                            float* __restrict__ out, int K) {
  int row  = blockIdx.x * 4 + (threadIdx.x >> 6);
  int lane = threadIdx.x & 63;
  const unsigned short* ap = Abf + (size_t)row * K;
  float s = 0.f;
  for (int k = lane * 8; k < K; k += 512) {
    u16x8 v = *(const u16x8*)(ap + k);
#pragma unroll
    for (int j = 0; j < 8; ++j) s += bf2f(v[j]) * wvec[k + j];
  }
#pragma unroll
  for (int off = 32; off; off >>= 1) s += __shfl_down(s, off);
  if (lane == 0) out[row] = s + bias[0];
}

// ---------------------------------------------------------------------------
extern "C" void kernel_launch(void* const* d_in, const int* in_sizes, int n_in,
                              void* d_out, int out_size, void* d_ws, size_t ws_size,
                              hipStream_t stream) {
  const float* x     = (const float*)d_in[0];
  const float* field = (const float*)d_in[1];
  const float* fw1   = (const float*)d_in[2];
  const float* fb1   = (const float*)d_in[3];
  const float* fw2   = (const float*)d_in[4];
  const float* fb2   = (const float*)d_in[5];
  const float* ww1   = (const float*)d_in[6];
  const float* wb1   = (const float*)d_in[7];
  const float* ww2   = (const float*)d_in[8];
  const float* wb2   = (const float*)d_in[9];
  const float* ww3   = (const float*)d_in[10];
  const float* wb3   = (const float*)d_in[11];
  const float* tw1   = (const float*)d_in[12];
  const float* tb1   = (const float*)d_in[13];
  const float* tw2   = (const float*)d_in[14];
  const float* tb2   = (const float*)d_in[15];

  const int M = 16384;
  float* outF    = (float*)d_out;                  // field_output [16384,4096]
  float* outWil  = outF + (size_t)M * 4096;        // wilson [16384]
  float* outTop  = outWil + M;                     // topology [16384]
  float* outPlaq = outTop + M;                     // plaq [1]

  char* ws = (char*)d_ws;
  unsigned short* hbuf  = (unsigned short*)(ws);                // h, later w2 (64MB)
  unsigned short* fobuf = (unsigned short*)(ws + 67108864);     // field_output bf16 (128MB)
  unsigned short* cbuf  = (unsigned short*)(ws + 201326592);    // w1, later t (64MB)
  unsigned short* wslot = (unsigned short*)(ws + 268435456);    // rotating WT slot (16MB)
  unsigned short* w2buf = hbuf;

  const int SMEM = 131072;   // 128 KB dynamic LDS for the ring
  (void)hipFuncSetAttribute((const void*)gemm256_kernel<0,1,1>,
                            hipFuncAttributeMaxDynamicSharedMemorySize, SMEM);
  (void)hipFuncSetAttribute((const void*)gemm256_kernel<1,0,1>,
                            hipFuncAttributeMaxDynamicSharedMemorySize, SMEM);

  // plaquette (scalar)
  hipLaunchKernelGGL(plaq_kernel, dim3(1), dim3(64), 0, stream, x, field, outPlaq);

  // h = relu(x @ fw1 + fb1) -> bf16
  hipLaunchKernelGGL(fc1_kernel, dim3(16384), dim3(256), 0, stream, x, fw1, fb1, hbuf);

  // field_output = h @ fw2 + fb2  (f32 -> d_out, bf16 -> ws)
  hipLaunchKernelGGL(transpose_bf16_kernel, dim3(128, 64), dim3(32, 8), 0, stream,
                     fw2, wslot, 2048, 4096);
  hipLaunchKernelGGL((gemm256_kernel<0, 1, 1>), dim3(64 * 16), dim3(512), SMEM, stream,
                     hbuf, wslot, fb2, outF, fobuf, 4096, 2048, 64);

  // w1 = relu(fo @ ww1 + wb1)
  hipLaunchKernelGGL(transpose_bf16_kernel, dim3(64, 128), dim3(32, 8), 0, stream,
                     ww1, wslot, 4096, 2048);
  hipLaunchKernelGGL((gemm256_kernel<1, 0, 1>), dim3(64 * 8), dim3(512), SMEM, stream,
                     fobuf, wslot, wb1, (float*)nullptr, cbuf, 2048, 4096, 64);

  // w2 = relu(w1 @ ww2 + wb2)
  hipLaunchKernelGGL(transpose_bf16_kernel, dim3(32, 64), dim3(32, 8), 0, stream,
                     ww2, wslot, 2048, 1024);
  hipLaunchKernelGGL((gemm256_kernel<1, 0, 1>), dim3(64 * 4), dim3(512), SMEM, stream,
                     cbuf, wslot, wb2, (float*)nullptr, w2buf, 1024, 2048, 64);

  // wilson_output = w2 @ ww3 + wb3
  hipLaunchKernelGGL(gemv_kernel, dim3(4096), dim3(256), 0, stream,
                     w2buf, ww3, wb3, outWil, 1024);

  // t = relu(fo @ tw1 + tb1)
  hipLaunchKernelGGL(transpose_bf16_kernel, dim3(64, 128), dim3(32, 8), 0, stream,
                     tw1, wslot, 4096, 2048);
  hipLaunchKernelGGL((gemm256_kernel<1, 0, 1>), dim3(64 * 8), dim3(512), SMEM, stream,
                     fobuf, wslot, tb1, (float*)nullptr, cbuf, 2048, 4096, 64);

  // topology_output = t @ tw2 + tb2
  hipLaunchKernelGGL(gemv_kernel, dim3(4096), dim3(256), 0, stream,
                     cbuf, tw2, tb2, outTop, 2048);

  (void)in_sizes; (void)n_in; (void)out_size; (void)ws_size;
}

// Round 3
// 1060.828 us; speedup vs baseline: 1.1628x; 1.0331x over previous
//
#include <hip/hip_runtime.h>

#define L 10

using bf16x8 = __attribute__((ext_vector_type(8))) __bf16;
using u16x8  = __attribute__((ext_vector_type(8))) unsigned short;
using f32x4  = __attribute__((ext_vector_type(4))) float;

__device__ __forceinline__ unsigned short f2bf(float f) {
  unsigned int u = __float_as_uint(f);
  u += 0x7FFFu + ((u >> 16) & 1u);          // RNE
  return (unsigned short)(u >> 16);
}
__device__ __forceinline__ float bf2f(unsigned short h) {
  return __uint_as_float(((unsigned int)h) << 16);
}

// ---------------------------------------------------------------------------
// Plaquette: single thread, exact fp32, matching JAX trunc-cast + python mod.
// ---------------------------------------------------------------------------
__global__ void plaq_kernel(const float* __restrict__ x,
                            const float* __restrict__ field,
                            float* __restrict__ out) {
  if (threadIdx.x != 0 || blockIdx.x != 0) return;
  int c[4];
#pragma unroll
  for (int i = 0; i < 4; ++i) {
    int v = (int)x[i];
    v %= L; if (v < 0) v += L;
    c[i] = v;
  }
  float S = 0.f;
  for (int mu = 0; mu < 4; ++mu)
    for (int nu = mu + 1; nu < 4; ++nu) {
      int p[4] = {c[0], c[1], c[2], c[3]};
      float l1 = field[((p[0]*L + p[1])*L + p[2])*4 + mu];
      p[mu] = (p[mu] + 1) % L;
      float l2 = field[((p[0]*L + p[1])*L + p[2])*4 + nu];
      p[nu] = (p[nu] + 1) % L;
      float l3 = field[((p[0]*L + p[1])*L + p[2])*4 + mu];
      float l4 = field[((c[0]*L + c[1])*L + c[2])*4 + nu];
      S += l1 + l2 - l3 - l4;
    }
  out[0] = expf(S);
}

// ---------------------------------------------------------------------------
// fc1: h = relu(x[16384,4] @ fw1[4,2048] + fb1) -> bf16.
// ---------------------------------------------------------------------------
__global__ void fc1_kernel(const float* __restrict__ x,
                           const float* __restrict__ fw1,
                           const float* __restrict__ fb1,
                           unsigned short* __restrict__ h) {
  const int N = 2048;
  int idx = blockIdx.x * blockDim.x + threadIdx.x;
  int m  = idx >> 8;
  int n0 = (idx & 255) * 8;
  float4 xv = *(const float4*)(x + (size_t)m * 4);
  unsigned short o[8];
#pragma unroll
  for (int j = 0; j < 8; ++j) {
    int n = n0 + j;
    float s = fb1[n] + xv.x * fw1[n] + xv.y * fw1[N + n]
                     + xv.z * fw1[2*N + n] + xv.w * fw1[3*N + n];
    o[j] = f2bf(fmaxf(s, 0.f));
  }
  *(u16x8*)(h + (size_t)m * N + n0) = *(const u16x8*)o;
}

// ---------------------------------------------------------------------------
// Weight transpose+convert: W[K][N] f32 -> WT[N][K] bf16.
// ---------------------------------------------------------------------------
__global__ void transpose_bf16_kernel(const float* __restrict__ W,
                                      unsigned short* __restrict__ WT,
                                      int K, int N) {
  __shared__ float tile[32][33];
  int n0 = blockIdx.x * 32, k0 = blockIdx.y * 32;
  int tx = threadIdx.x, ty = threadIdx.y;   // 32 x 8
#pragma unroll
  for (int i = 0; i < 32; i += 8)
    tile[ty + i][tx] = W[(size_t)(k0 + ty + i) * N + n0 + tx];
  __syncthreads();
#pragma unroll
  for (int i = 0; i < 32; i += 8)
    WT[(size_t)(n0 + ty + i) * K + k0 + tx] = f2bf(tile[tx][ty + i]);
}

// ---------------------------------------------------------------------------
// 256x256 bf16 MFMA GEMM, K32 slots, ring of 4 (128KB), 8 waves (2Mx4N).
// Two 16-MFMA phases per K32 tile (m201-style), inline-asm ds_read_b128
// (defeats compiler vmcnt insertion), counted vmcnt(8) (T4), zero-conflict
// XOR swizzle (T2), setprio around MFMA clusters (T5), XCD swizzle (T1).
// C = act(A[M,K] @ BT[N,K]^T + bias).
// ---------------------------------------------------------------------------
#define GLL(gp, lp)                                                            \
  __builtin_amdgcn_global_load_lds(                                            \
      (const __attribute__((address_space(1))) unsigned int*)(gp),             \
      (__attribute__((address_space(3))) unsigned int*)(lp), 16, 0, 0)

#define DSREAD(dst, addr)                                                      \
  asm volatile("ds_read_b128 %0, %1" : "=v"(dst) : "v"(addr))

#define FENCE() asm volatile("" ::: "memory")

extern __shared__ char lds_raw[];

template<int RELU, int SF32, int SBF16>
__global__ __launch_bounds__(512)
void gemm256_kernel(const unsigned short* __restrict__ A,
                    const unsigned short* __restrict__ BT,
                    const float* __restrict__ bias,
                    float* __restrict__ outF,
                    unsigned short* __restrict__ outB,
                    int N, int K, int gmx) {
  const int NT = K >> 5;                      // K32 tiles

  // T1: bijective XCD swizzle, bm fastest
  const int nwg = gridDim.x;
  const int q = nwg >> 3, r = nwg & 7;
  const int xcd = blockIdx.x & 7, lid = blockIdx.x >> 3;
  const int wg2 = (xcd < r ? xcd * (q + 1) : r * (q + 1) + (xcd - r) * q) + lid;
  const int bm = wg2 % gmx, bn = wg2 / gmx;

  const int tid  = threadIdx.x;
  const int wid  = tid >> 6, lane = tid & 63;
  const int wr   = wid >> 2, wc = wid & 3;          // 2 x 4 waves
  const int lr   = lane & 15, lg = lane >> 4;

  // ---- staging (block-uniform): slot = 32KB = A[256][32] + B[256][32] ----
  // thread t writes storage row rw = c*128 + (t>>2), chunk sc = t&3 (16B);
  // swizzle: global chunk gc = sc ^ ((rw>>1)&3) = (t&3)^((t>>3)&3)
  const int srow = tid >> 2;
  const int scol = ((tid & 3) ^ ((tid >> 3) & 3)) * 8;   // elems
  const unsigned short* agp0 = A  + (size_t)(bm * 256 + srow) * K + scol;
  const unsigned short* agp1 = agp0 + (size_t)128 * K;
  const unsigned short* bgp0 = BT + (size_t)(bn * 256 + srow) * K + scol;
  const unsigned short* bgp1 = bgp0 + (size_t)128 * K;

  // ---- read-side swizzled fragment offsets (bank-conflict-free, r2-proven) --
  const int chunk = lg ^ ((lr >> 1) & 3);
  const unsigned ldsbase = (unsigned)(uintptr_t)&lds_raw[0];
  const unsigned aoff = (unsigned)((wr * 128 + lr) * 64 + chunk * 16);
  const unsigned boff = (unsigned)(16384 + (wc * 64 + lr) * 64 + chunk * 16);

  f32x4 acc[8][4];
#pragma unroll
  for (int m = 0; m < 8; ++m)
#pragma unroll
    for (int n = 0; n < 4; ++n) acc[m][n] = (f32x4)0.f;

#define STAGE_A(tt) do { unsigned so = (unsigned)(((tt) & 3) << 15);           \
    GLL(agp0 + (size_t)(tt) * 32, lds_raw + so + tid * 16);                    \
    GLL(agp1 + (size_t)(tt) * 32, lds_raw + so + 8192 + tid * 16); } while (0)
#define STAGE_B(tt) do { unsigned so = (unsigned)(((tt) & 3) << 15);           \
    GLL(bgp0 + (size_t)(tt) * 32, lds_raw + so + 16384 + tid * 16);            \
    GLL(bgp1 + (size_t)(tt) * 32, lds_raw + so + 24576 + tid * 16); } while (0)

  // prologue: tiles 0,1,2 staged (12 loads in flight)
  STAGE_A(0); STAGE_B(0); STAGE_A(1); STAGE_B(1); STAGE_A(2); STAGE_B(2);

  for (int t = 0; t < NT; ++t) {
    const int rem = NT - 1 - t;
    // gate slot t (4 oldest loads) while keeping 8 in flight (T4)
    if (rem >= 2)      asm volatile("s_waitcnt vmcnt(8)" ::: "memory");
    else if (rem == 1) asm volatile("s_waitcnt vmcnt(4)" ::: "memory");
    else               asm volatile("s_waitcnt vmcnt(0)" ::: "memory");
    FENCE(); __builtin_amdgcn_s_barrier(); FENCE();

    const unsigned sbase = ldsbase + (unsigned)((t & 3) << 15);

    // ---- P0: read a[0..3] + b[0..3], stage A(t+3), MFMA m0-3 x n0-3 ----
    u16x8 a[4], b[4];
    DSREAD(b[0], sbase + boff);
    DSREAD(b[1], sbase + boff + 1024);
    DSREAD(b[2], sbase + boff + 2048);
    DSREAD(b[3], sbase + boff + 3072);
    DSREAD(a[0], sbase + aoff);
    DSREAD(a[1], sbase + aoff + 1024);
    DSREAD(a[2], sbase + aoff + 2048);
    DSREAD(a[3], sbase + aoff + 3072);
    if (t + 3 < NT) STAGE_A(t + 3);
    __builtin_amdgcn_sched_barrier(0);
    FENCE(); __builtin_amdgcn_s_barrier(); FENCE();
    asm volatile("s_waitcnt lgkmcnt(0)" ::: "memory");
    __builtin_amdgcn_sched_barrier(0);
    __builtin_amdgcn_s_setprio(1);
#pragma unroll
    for (int m = 0; m < 4; ++m)
#pragma unroll
      for (int n = 0; n < 4; ++n)
        acc[m][n] = __builtin_amdgcn_mfma_f32_16x16x32_bf16(
            __builtin_bit_cast(bf16x8, a[m]),
            __builtin_bit_cast(bf16x8, b[n]),
            acc[m][n], 0, 0, 0);
    __builtin_amdgcn_s_setprio(0);
    __builtin_amdgcn_sched_barrier(0);

    // ---- P1: read a[4..7], stage B(t+3), MFMA m4-7 x n0-3 ----
    u16x8 a2[4];
    DSREAD(a2[0], sbase + aoff + 4096);
    DSREAD(a2[1], sbase + aoff + 5120);
    DSREAD(a2[2], sbase + aoff + 6144);
    DSREAD(a2[3], sbase + aoff + 7168);
    if (t + 3 < NT) STAGE_B(t + 3);
    __builtin_amdgcn_sched_barrier(0);
    FENCE(); __builtin_amdgcn_s_barrier(); FENCE();
    asm volatile("s_waitcnt lgkmcnt(0)" ::: "memory");
    __builtin_amdgcn_sched_barrier(0);
    __builtin_amdgcn_s_setprio(1);
#pragma unroll
    for (int m = 0; m < 4; ++m)
#pragma unroll
      for (int n = 0; n < 4; ++n)
        acc[m + 4][n] = __builtin_amdgcn_mfma_f32_16x16x32_bf16(
            __builtin_bit_cast(bf16x8, a2[m]),
            __builtin_bit_cast(bf16x8, b[n]),
            acc[m + 4][n], 0, 0, 0);
    __builtin_amdgcn_s_setprio(0);
    __builtin_amdgcn_sched_barrier(0);
  }
#undef STAGE_A
#undef STAGE_B

  // epilogue: D row = lg*4 + j (within m*16), col = lr (within n*16)
  const int rowBase = bm * 256 + wr * 128 + lg * 4;
  const int colBase = bn * 256 + wc * 64 + lr;
#pragma unroll
  for (int n = 0; n < 4; ++n) {
    int col = colBase + n * 16;
    float bv = bias[col];
#pragma unroll
    for (int m = 0; m < 8; ++m) {
      int row = rowBase + m * 16;
#pragma unroll
      for (int j = 0; j < 4; ++j) {
        float v = acc[m][n][j] + bv;
        if (RELU) v = fmaxf(v, 0.f);
        size_t o = (size_t)(row + j) * N + col;
        if (SF32)  outF[o] = v;
        if (SBF16) outB[o] = f2bf(v);
      }
    }
  }
}

// ---------------------------------------------------------------------------
// GEMV head: out[m] = sum_k A[m,k]*w[k] + b.  One wave per row.
// ---------------------------------------------------------------------------
__global__ void gemv_kernel(const unsigned short* __restrict__ Abf,
                            const float* __restrict__ wvec,
                            const float* __restrict__ bias,
                            float* __restrict__ out, int K) {
  int row  = blockIdx.x * 4 + (threadIdx.x >> 6);
  int lane = threadIdx.x & 63;
  const unsigned short* ap = Abf + (size_t)row * K;
  float s = 0.f;
  for (int k = lane * 8; k < K; k += 512) {
    u16x8 v = *(const u16x8*)(ap + k);
#pragma unroll
    for (int j = 0; j < 8; ++j) s += bf2f(v[j]) * wvec[k + j];
  }
#pragma unroll
  for (int off = 32; off; off >>= 1) s += __shfl_down(s, off);
  if (lane == 0) out[row] = s + bias[0];
}

// ---------------------------------------------------------------------------
extern "C" void kernel_launch(void* const* d_in, const int* in_sizes, int n_in,
                              void* d_out, int out_size, void* d_ws, size_t ws_size,
                              hipStream_t stream) {
  const float* x     = (const float*)d_in[0];
  const float* field = (const float*)d_in[1];
  const float* fw1   = (const float*)d_in[2];
  const float* fb1   = (const float*)d_in[3];
  const float* fw2   = (const float*)d_in[4];
  const float* fb2   = (const float*)d_in[5];
  const float* ww1   = (const float*)d_in[6];
  const float* wb1   = (const float*)d_in[7];
  const float* ww2   = (const float*)d_in[8];
  const float* wb2   = (const float*)d_in[9];
  const float* ww3   = (const float*)d_in[10];
  const float* wb3   = (const float*)d_in[11];
  const float* tw1   = (const float*)d_in[12];
  const float* tb1   = (const float*)d_in[13];
  const float* tw2   = (const float*)d_in[14];
  const float* tb2   = (const float*)d_in[15];

  const int M = 16384;
  float* outF    = (float*)d_out;                  // field_output [16384,4096]
  float* outWil  = outF + (size_t)M * 4096;        // wilson [16384]
  float* outTop  = outWil + M;                     // topology [16384]
  float* outPlaq = outTop + M;                     // plaq [1]

  char* ws = (char*)d_ws;
  unsigned short* hbuf  = (unsigned short*)(ws);                // h, later w2 (64MB)
  unsigned short* fobuf = (unsigned short*)(ws + 67108864);     // field_output bf16 (128MB)
  unsigned short* cbuf  = (unsigned short*)(ws + 201326592);    // w1, later t (64MB)
  unsigned short* wslot = (unsigned short*)(ws + 268435456);    // rotating WT slot (16MB)
  unsigned short* w2buf = hbuf;

  const int SMEM = 131072;   // 128 KB dynamic LDS (4-slot ring)
  (void)hipFuncSetAttribute((const void*)gemm256_kernel<0,1,1>,
                            hipFuncAttributeMaxDynamicSharedMemorySize, SMEM);
  (void)hipFuncSetAttribute((const void*)gemm256_kernel<1,0,1>,
                            hipFuncAttributeMaxDynamicSharedMemorySize, SMEM);

  // plaquette (scalar)
  hipLaunchKernelGGL(plaq_kernel, dim3(1), dim3(64), 0, stream, x, field, outPlaq);

  // h = relu(x @ fw1 + fb1) -> bf16
  hipLaunchKernelGGL(fc1_kernel, dim3(16384), dim3(256), 0, stream, x, fw1, fb1, hbuf);

  // field_output = h @ fw2 + fb2  (f32 -> d_out, bf16 -> ws)
  hipLaunchKernelGGL(transpose_bf16_kernel, dim3(128, 64), dim3(32, 8), 0, stream,
                     fw2, wslot, 2048, 4096);
  hipLaunchKernelGGL((gemm256_kernel<0, 1, 1>), dim3(64 * 16), dim3(512), SMEM, stream,
                     hbuf, wslot, fb2, outF, fobuf, 4096, 2048, 64);

  // w1 = relu(fo @ ww1 + wb1)
  hipLaunchKernelGGL(transpose_bf16_kernel, dim3(64, 128), dim3(32, 8), 0, stream,
                     ww1, wslot, 4096, 2048);
  hipLaunchKernelGGL((gemm256_kernel<1, 0, 1>), dim3(64 * 8), dim3(512), SMEM, stream,
                     fobuf, wslot, wb1, (float*)nullptr, cbuf, 2048, 4096, 64);

  // w2 = relu(w1 @ ww2 + wb2)
  hipLaunchKernelGGL(transpose_bf16_kernel, dim3(32, 64), dim3(32, 8), 0, stream,
                     ww2, wslot, 2048, 1024);
  hipLaunchKernelGGL((gemm256_kernel<1, 0, 1>), dim3(64 * 4), dim3(512), SMEM, stream,
                     cbuf, wslot, wb2, (float*)nullptr, w2buf, 1024, 2048, 64);

  // wilson_output = w2 @ ww3 + wb3
  hipLaunchKernelGGL(gemv_kernel, dim3(4096), dim3(256), 0, stream,
                     w2buf, ww3, wb3, outWil, 1024);

  // t = relu(fo @ tw1 + tb1)
  hipLaunchKernelGGL(transpose_bf16_kernel, dim3(64, 128), dim3(32, 8), 0, stream,
                     tw1, wslot, 4096, 2048);
  hipLaunchKernelGGL((gemm256_kernel<1, 0, 1>), dim3(64 * 8), dim3(512), SMEM, stream,
                     fobuf, wslot, tb1, (float*)nullptr, cbuf, 2048, 4096, 64);

  // topology_output = t @ tw2 + tb2
  hipLaunchKernelGGL(gemv_kernel, dim3(4096), dim3(256), 0, stream,
                     cbuf, tw2, tb2, outTop, 2048);

  (void)in_sizes; (void)n_in; (void)out_size; (void)ws_size;
}

// Round 4
// 1029.671 us; speedup vs baseline: 1.1980x; 1.0303x over previous
//
#include <hip/hip_runtime.h>

#define L 10

using bf16x8 = __attribute__((ext_vector_type(8))) __bf16;
using u16x8  = __attribute__((ext_vector_type(8))) unsigned short;
using f32x4  = __attribute__((ext_vector_type(4))) float;

__device__ __forceinline__ unsigned short f2bf(float f) {
  unsigned int u = __float_as_uint(f);
  u += 0x7FFFu + ((u >> 16) & 1u);          // RNE
  return (unsigned short)(u >> 16);
}
__device__ __forceinline__ float bf2f(unsigned short h) {
  return __uint_as_float(((unsigned int)h) << 16);
}

// ---------------------------------------------------------------------------
// Plaquette: single thread, exact fp32, matching JAX trunc-cast + python mod.
// ---------------------------------------------------------------------------
__global__ void plaq_kernel(const float* __restrict__ x,
                            const float* __restrict__ field,
                            float* __restrict__ out) {
  if (threadIdx.x != 0 || blockIdx.x != 0) return;
  int c[4];
#pragma unroll
  for (int i = 0; i < 4; ++i) {
    int v = (int)x[i];
    v %= L; if (v < 0) v += L;
    c[i] = v;
  }
  float S = 0.f;
  for (int mu = 0; mu < 4; ++mu)
    for (int nu = mu + 1; nu < 4; ++nu) {
      int p[4] = {c[0], c[1], c[2], c[3]};
      float l1 = field[((p[0]*L + p[1])*L + p[2])*4 + mu];
      p[mu] = (p[mu] + 1) % L;
      float l2 = field[((p[0]*L + p[1])*L + p[2])*4 + nu];
      p[nu] = (p[nu] + 1) % L;
      float l3 = field[((p[0]*L + p[1])*L + p[2])*4 + mu];
      float l4 = field[((c[0]*L + c[1])*L + c[2])*4 + nu];
      S += l1 + l2 - l3 - l4;
    }
  out[0] = expf(S);
}

// ---------------------------------------------------------------------------
// fc1: h = relu(x[16384,4] @ fw1[4,2048] + fb1) -> bf16.
// ---------------------------------------------------------------------------
__global__ void fc1_kernel(const float* __restrict__ x,
                           const float* __restrict__ fw1,
                           const float* __restrict__ fb1,
                           unsigned short* __restrict__ h) {
  const int N = 2048;
  int idx = blockIdx.x * blockDim.x + threadIdx.x;
  int m  = idx >> 8;
  int n0 = (idx & 255) * 8;
  float4 xv = *(const float4*)(x + (size_t)m * 4);
  unsigned short o[8];
#pragma unroll
  for (int j = 0; j < 8; ++j) {
    int n = n0 + j;
    float s = fb1[n] + xv.x * fw1[n] + xv.y * fw1[N + n]
                     + xv.z * fw1[2*N + n] + xv.w * fw1[3*N + n];
    o[j] = f2bf(fmaxf(s, 0.f));
  }
  *(u16x8*)(h + (size_t)m * N + n0) = *(const u16x8*)o;
}

// ---------------------------------------------------------------------------
// Weight transpose+convert: W[K][N] f32 -> WT[N][K] bf16.
// ---------------------------------------------------------------------------
__global__ void transpose_bf16_kernel(const float* __restrict__ W,
                                      unsigned short* __restrict__ WT,
                                      int K, int N) {
  __shared__ float tile[32][33];
  int n0 = blockIdx.x * 32, k0 = blockIdx.y * 32;
  int tx = threadIdx.x, ty = threadIdx.y;   // 32 x 8
#pragma unroll
  for (int i = 0; i < 32; i += 8)
    tile[ty + i][tx] = W[(size_t)(k0 + ty + i) * N + n0 + tx];
  __syncthreads();
#pragma unroll
  for (int i = 0; i < 32; i += 8)
    WT[(size_t)(n0 + ty + i) * K + k0 + tx] = f2bf(tile[tx][ty + i]);
}

// ---------------------------------------------------------------------------
// 256x256 bf16 MFMA GEMM, K32 slots, ring of 4 (128KB), 8 waves (2Mx4N).
// One barrier/tile; asm ds_read (keeps vmcnt counted, T4) consumed via
// COUNTED lgkmcnt clusters (LDS service hides under MFMA); zero-conflict
// XOR swizzle (T2); setprio (T5); bijective XCD swizzle (T1).
// C = act(A[M,K] @ BT[N,K]^T + bias).
// ---------------------------------------------------------------------------
#define GLL(gp, lp)                                                            \
  __builtin_amdgcn_global_load_lds(                                            \
      (const __attribute__((address_space(1))) unsigned int*)(gp),             \
      (__attribute__((address_space(3))) unsigned int*)(lp), 16, 0, 0)

#define DSREAD(dst, addr)                                                      \
  asm volatile("ds_read_b128 %0, %1" : "=v"(dst) : "v"(addr))

#define LGKM(n)                                                                \
  do { asm volatile("s_waitcnt lgkmcnt(" #n ")" ::: "memory");                 \
       __builtin_amdgcn_sched_barrier(0); } while (0)

#define FENCE() asm volatile("" ::: "memory")

extern __shared__ char lds_raw[];

template<int RELU, int SF32, int SBF16>
__global__ __launch_bounds__(512)
void gemm256_kernel(const unsigned short* __restrict__ A,
                    const unsigned short* __restrict__ BT,
                    const float* __restrict__ bias,
                    float* __restrict__ outF,
                    unsigned short* __restrict__ outB,
                    int N, int K, int gmx) {
  const int NT = K >> 5;                      // K32 tiles

  // T1: bijective XCD swizzle, bm fastest
  const int nwg = gridDim.x;
  const int q = nwg >> 3, r = nwg & 7;
  const int xcd = blockIdx.x & 7, lid = blockIdx.x >> 3;
  const int wg2 = (xcd < r ? xcd * (q + 1) : r * (q + 1) + (xcd - r) * q) + lid;
  const int bm = wg2 % gmx, bn = wg2 / gmx;

  const int tid  = threadIdx.x;
  const int wid  = tid >> 6, lane = tid & 63;
  const int wr   = wid >> 2, wc = wid & 3;          // 2 x 4 waves
  const int lr   = lane & 15, lg = lane >> 4;

  // ---- staging (pre-swizzled global source, linear LDS dest) ----
  const int srow = tid >> 2;
  const int scol = ((tid & 3) ^ ((tid >> 3) & 3)) * 8;   // elems
  const unsigned short* agp0 = A  + (size_t)(bm * 256 + srow) * K + scol;
  const unsigned short* agp1 = agp0 + (size_t)128 * K;
  const unsigned short* bgp0 = BT + (size_t)(bn * 256 + srow) * K + scol;
  const unsigned short* bgp1 = bgp0 + (size_t)128 * K;

  // ---- read-side swizzled fragment offsets (0 bank conflicts, r2-proven) --
  const int chunk = lg ^ ((lr >> 1) & 3);
  const unsigned ldsbase = (unsigned)(uintptr_t)&lds_raw[0];
  const unsigned aoff = (unsigned)((wr * 128 + lr) * 64 + chunk * 16);
  const unsigned boff = (unsigned)(16384 + (wc * 64 + lr) * 64 + chunk * 16);

  f32x4 acc[8][4];
#pragma unroll
  for (int m = 0; m < 8; ++m)
#pragma unroll
    for (int n = 0; n < 4; ++n) acc[m][n] = (f32x4)0.f;

#define STAGE_A(tt) do { unsigned so = (unsigned)(((tt) & 3) << 15);           \
    GLL(agp0 + (size_t)(tt) * 32, lds_raw + so + tid * 16);                    \
    GLL(agp1 + (size_t)(tt) * 32, lds_raw + so + 8192 + tid * 16); } while (0)
#define STAGE_B(tt) do { unsigned so = (unsigned)(((tt) & 3) << 15);           \
    GLL(bgp0 + (size_t)(tt) * 32, lds_raw + so + 16384 + tid * 16);            \
    GLL(bgp1 + (size_t)(tt) * 32, lds_raw + so + 24576 + tid * 16); } while (0)

  // prologue: tiles 0,1,2 staged (12 loads in flight)
  STAGE_A(0); STAGE_B(0); STAGE_A(1); STAGE_B(1); STAGE_A(2); STAGE_B(2);

  for (int t = 0; t < NT; ++t) {
    const int rem = NT - 1 - t;
    // gate slot t (oldest 4 loads) while keeping up to 8 in flight (T4)
    if (rem >= 2)      asm volatile("s_waitcnt vmcnt(8)" ::: "memory");
    else if (rem == 1) asm volatile("s_waitcnt vmcnt(4)" ::: "memory");
    else               asm volatile("s_waitcnt vmcnt(0)" ::: "memory");
    FENCE(); __builtin_amdgcn_s_barrier(); FENCE();
    __builtin_amdgcn_sched_barrier(0);

    const unsigned sbase = ldsbase + (unsigned)((t & 3) << 15);

    // issue ALL reads in consumption order: b0-3 then a0-7 (in-order DS rets)
    u16x8 b[4], a[8];
    DSREAD(b[0], sbase + boff);
    DSREAD(b[1], sbase + boff + 1024);
    DSREAD(b[2], sbase + boff + 2048);
    DSREAD(b[3], sbase + boff + 3072);
    DSREAD(a[0], sbase + aoff);
    DSREAD(a[1], sbase + aoff + 1024);
    DSREAD(a[2], sbase + aoff + 2048);
    DSREAD(a[3], sbase + aoff + 3072);
    DSREAD(a[4], sbase + aoff + 4096);
    DSREAD(a[5], sbase + aoff + 5120);
    DSREAD(a[6], sbase + aoff + 6144);
    DSREAD(a[7], sbase + aoff + 7168);
    // stage tile t+3 into slot (t-1)&3 — safe after this tile's barrier
    if (t + 3 < NT) { STAGE_A(t + 3); STAGE_B(t + 3); }

    // 8 clusters: counted lgkm gate -> 4 MFMA; LDS serves ahead under MFMA
    __builtin_amdgcn_s_setprio(1);
#define CLUSTER(m, g)                                                          \
    LGKM(g);                                                                   \
    acc[m][0] = __builtin_amdgcn_mfma_f32_16x16x32_bf16(                       \
        __builtin_bit_cast(bf16x8, a[m]), __builtin_bit_cast(bf16x8, b[0]),    \
        acc[m][0], 0, 0, 0);                                                   \
    acc[m][1] = __builtin_amdgcn_mfma_f32_16x16x32_bf16(                       \
        __builtin_bit_cast(bf16x8, a[m]), __builtin_bit_cast(bf16x8, b[1]),    \
        acc[m][1], 0, 0, 0);                                                   \
    acc[m][2] = __builtin_amdgcn_mfma_f32_16x16x32_bf16(                       \
        __builtin_bit_cast(bf16x8, a[m]), __builtin_bit_cast(bf16x8, b[2]),    \
        acc[m][2], 0, 0, 0);                                                   \
    acc[m][3] = __builtin_amdgcn_mfma_f32_16x16x32_bf16(                       \
        __builtin_bit_cast(bf16x8, a[m]), __builtin_bit_cast(bf16x8, b[3]),    \
        acc[m][3], 0, 0, 0)

    CLUSTER(0, 7);
    CLUSTER(1, 6);
    CLUSTER(2, 5);
    CLUSTER(3, 4);
    CLUSTER(4, 3);
    CLUSTER(5, 2);
    CLUSTER(6, 1);
    CLUSTER(7, 0);
#undef CLUSTER
    __builtin_amdgcn_s_setprio(0);
    __builtin_amdgcn_sched_barrier(0);
  }
#undef STAGE_A
#undef STAGE_B

  // epilogue: D row = lg*4 + j (within m*16), col = lr (within n*16)
  const int rowBase = bm * 256 + wr * 128 + lg * 4;
  const int colBase = bn * 256 + wc * 64 + lr;
#pragma unroll
  for (int n = 0; n < 4; ++n) {
    int col = colBase + n * 16;
    float bv = bias[col];
#pragma unroll
    for (int m = 0; m < 8; ++m) {
      int row = rowBase + m * 16;
#pragma unroll
      for (int j = 0; j < 4; ++j) {
        float v = acc[m][n][j] + bv;
        if (RELU) v = fmaxf(v, 0.f);
        size_t o = (size_t)(row + j) * N + col;
        if (SF32)  outF[o] = v;
        if (SBF16) outB[o] = f2bf(v);
      }
    }
  }
}

// ---------------------------------------------------------------------------
// GEMV head: out[m] = sum_k A[m,k]*w[k] + b.  One wave per row.
// ---------------------------------------------------------------------------
__global__ void gemv_kernel(const unsigned short* __restrict__ Abf,
                            const float* __restrict__ wvec,
                            const float* __restrict__ bias,
                            float* __restrict__ out, int K) {
  int row  = blockIdx.x * 4 + (threadIdx.x >> 6);
  int lane = threadIdx.x & 63;
  const unsigned short* ap = Abf + (size_t)row * K;
  float s = 0.f;
  for (int k = lane * 8; k < K; k += 512) {
    u16x8 v = *(const u16x8*)(ap + k);
#pragma unroll
    for (int j = 0; j < 8; ++j) s += bf2f(v[j]) * wvec[k + j];
  }
#pragma unroll
  for (int off = 32; off; off >>= 1) s += __shfl_down(s, off);
  if (lane == 0) out[row] = s + bias[0];
}

// ---------------------------------------------------------------------------
extern "C" void kernel_launch(void* const* d_in, const int* in_sizes, int n_in,
                              void* d_out, int out_size, void* d_ws, size_t ws_size,
                              hipStream_t stream) {
  const float* x     = (const float*)d_in[0];
  const float* field = (const float*)d_in[1];
  const float* fw1   = (const float*)d_in[2];
  const float* fb1   = (const float*)d_in[3];
  const float* fw2   = (const float*)d_in[4];
  const float* fb2   = (const float*)d_in[5];
  const float* ww1   = (const float*)d_in[6];
  const float* wb1   = (const float*)d_in[7];
  const float* ww2   = (const float*)d_in[8];
  const float* wb2   = (const float*)d_in[9];
  const float* ww3   = (const float*)d_in[10];
  const float* wb3   = (const float*)d_in[11];
  const float* tw1   = (const float*)d_in[12];
  const float* tb1   = (const float*)d_in[13];
  const float* tw2   = (const float*)d_in[14];
  const float* tb2   = (const float*)d_in[15];

  const int M = 16384;
  float* outF    = (float*)d_out;                  // field_output [16384,4096]
  float* outWil  = outF + (size_t)M * 4096;        // wilson [16384]
  float* outTop  = outWil + M;                     // topology [16384]
  float* outPlaq = outTop + M;                     // plaq [1]

  char* ws = (char*)d_ws;
  unsigned short* hbuf  = (unsigned short*)(ws);                // h, later w2 (64MB)
  unsigned short* fobuf = (unsigned short*)(ws + 67108864);     // field_output bf16 (128MB)
  unsigned short* cbuf  = (unsigned short*)(ws + 201326592);    // w1, later t (64MB)
  unsigned short* wslot = (unsigned short*)(ws + 268435456);    // rotating WT slot (16MB)
  unsigned short* w2buf = hbuf;

  const int SMEM = 131072;   // 128 KB dynamic LDS (4-slot ring)
  (void)hipFuncSetAttribute((const void*)gemm256_kernel<0,1,1>,
                            hipFuncAttributeMaxDynamicSharedMemorySize, SMEM);
  (void)hipFuncSetAttribute((const void*)gemm256_kernel<1,0,1>,
                            hipFuncAttributeMaxDynamicSharedMemorySize, SMEM);

  // plaquette (scalar)
  hipLaunchKernelGGL(plaq_kernel, dim3(1), dim3(64), 0, stream, x, field, outPlaq);

  // h = relu(x @ fw1 + fb1) -> bf16
  hipLaunchKernelGGL(fc1_kernel, dim3(16384), dim3(256), 0, stream, x, fw1, fb1, hbuf);

  // field_output = h @ fw2 + fb2  (f32 -> d_out, bf16 -> ws)
  hipLaunchKernelGGL(transpose_bf16_kernel, dim3(128, 64), dim3(32, 8), 0, stream,
                     fw2, wslot, 2048, 4096);
  hipLaunchKernelGGL((gemm256_kernel<0, 1, 1>), dim3(64 * 16), dim3(512), SMEM, stream,
                     hbuf, wslot, fb2, outF, fobuf, 4096, 2048, 64);

  // w1 = relu(fo @ ww1 + wb1)
  hipLaunchKernelGGL(transpose_bf16_kernel, dim3(64, 128), dim3(32, 8), 0, stream,
                     ww1, wslot, 4096, 2048);
  hipLaunchKernelGGL((gemm256_kernel<1, 0, 1>), dim3(64 * 8), dim3(512), SMEM, stream,
                     fobuf, wslot, wb1, (float*)nullptr, cbuf, 2048, 4096, 64);

  // w2 = relu(w1 @ ww2 + wb2)
  hipLaunchKernelGGL(transpose_bf16_kernel, dim3(32, 64), dim3(32, 8), 0, stream,
                     ww2, wslot, 2048, 1024);
  hipLaunchKernelGGL((gemm256_kernel<1, 0, 1>), dim3(64 * 4), dim3(512), SMEM, stream,
                     cbuf, wslot, wb2, (float*)nullptr, w2buf, 1024, 2048, 64);

  // wilson_output = w2 @ ww3 + wb3
  hipLaunchKernelGGL(gemv_kernel, dim3(4096), dim3(256), 0, stream,
                     w2buf, ww3, wb3, outWil, 1024);

  // t = relu(fo @ tw1 + tb1)
  hipLaunchKernelGGL(transpose_bf16_kernel, dim3(64, 128), dim3(32, 8), 0, stream,
                     tw1, wslot, 4096, 2048);
  hipLaunchKernelGGL((gemm256_kernel<1, 0, 1>), dim3(64 * 8), dim3(512), SMEM, stream,
                     fobuf, wslot, tb1, (float*)nullptr, cbuf, 2048, 4096, 64);

  // topology_output = t @ tw2 + tb2
  hipLaunchKernelGGL(gemv_kernel, dim3(4096), dim3(256), 0, stream,
                     cbuf, tw2, tb2, outTop, 2048);

  (void)in_sizes; (void)n_in; (void)out_size; (void)ws_size;
}

// Round 5
// 898.457 us; speedup vs baseline: 1.3730x; 1.1460x over previous
//
#include <hip/hip_runtime.h>

#define L 10

using bf16x8 = __attribute__((ext_vector_type(8))) __bf16;
using u16x8  = __attribute__((ext_vector_type(8))) unsigned short;
using f32x4  = __attribute__((ext_vector_type(4))) float;

__device__ __forceinline__ unsigned short f2bf(float f) {
  unsigned int u = __float_as_uint(f);
  u += 0x7FFFu + ((u >> 16) & 1u);          // RNE
  return (unsigned short)(u >> 16);
}
__device__ __forceinline__ float bf2f(unsigned short h) {
  return __uint_as_float(((unsigned int)h) << 16);
}

// ---------------------------------------------------------------------------
// Plaquette: single thread, exact fp32, matching JAX trunc-cast + python mod.
// ---------------------------------------------------------------------------
__global__ void plaq_kernel(const float* __restrict__ x,
                            const float* __restrict__ field,
                            float* __restrict__ out) {
  if (threadIdx.x != 0 || blockIdx.x != 0) return;
  int c[4];
#pragma unroll
  for (int i = 0; i < 4; ++i) {
    int v = (int)x[i];
    v %= L; if (v < 0) v += L;
    c[i] = v;
  }
  float S = 0.f;
  for (int mu = 0; mu < 4; ++mu)
    for (int nu = mu + 1; nu < 4; ++nu) {
      int p[4] = {c[0], c[1], c[2], c[3]};
      float l1 = field[((p[0]*L + p[1])*L + p[2])*4 + mu];
      p[mu] = (p[mu] + 1) % L;
      float l2 = field[((p[0]*L + p[1])*L + p[2])*4 + nu];
      p[nu] = (p[nu] + 1) % L;
      float l3 = field[((p[0]*L + p[1])*L + p[2])*4 + mu];
      float l4 = field[((c[0]*L + c[1])*L + c[2])*4 + nu];
      S += l1 + l2 - l3 - l4;
    }
  out[0] = expf(S);
}

// ---------------------------------------------------------------------------
// fc1: h = relu(x[16384,4] @ fw1[4,2048] + fb1) -> bf16.
// ---------------------------------------------------------------------------
__global__ void fc1_kernel(const float* __restrict__ x,
                           const float* __restrict__ fw1,
                           const float* __restrict__ fb1,
                           unsigned short* __restrict__ h) {
  const int N = 2048;
  int idx = blockIdx.x * blockDim.x + threadIdx.x;
  int m  = idx >> 8;
  int n0 = (idx & 255) * 8;
  float4 xv = *(const float4*)(x + (size_t)m * 4);
  unsigned short o[8];
#pragma unroll
  for (int j = 0; j < 8; ++j) {
    int n = n0 + j;
    float s = fb1[n] + xv.x * fw1[n] + xv.y * fw1[N + n]
                     + xv.z * fw1[2*N + n] + xv.w * fw1[3*N + n];
    o[j] = f2bf(fmaxf(s, 0.f));
  }
  *(u16x8*)(h + (size_t)m * N + n0) = *(const u16x8*)o;
}

// ---------------------------------------------------------------------------
// Weight transpose+convert: W[K][N] f32 -> WT[N][K] bf16.
// ---------------------------------------------------------------------------
__global__ void transpose_bf16_kernel(const float* __restrict__ W,
                                      unsigned short* __restrict__ WT,
                                      int K, int N) {
  __shared__ float tile[32][33];
  int n0 = blockIdx.x * 32, k0 = blockIdx.y * 32;
  int tx = threadIdx.x, ty = threadIdx.y;   // 32 x 8
#pragma unroll
  for (int i = 0; i < 32; i += 8)
    tile[ty + i][tx] = W[(size_t)(k0 + ty + i) * N + n0 + tx];
  __syncthreads();
#pragma unroll
  for (int i = 0; i < 32; i += 8)
    WT[(size_t)(n0 + ty + i) * K + k0 + tx] = f2bf(tile[tx][ty + i]);
}

// ---------------------------------------------------------------------------
// Elementwise f32 -> bf16 cast (natural layout), 8 elems/thread.
// ---------------------------------------------------------------------------
__global__ void cast_bf16_kernel(const float* __restrict__ in,
                                 unsigned short* __restrict__ out) {
  size_t i = ((size_t)blockIdx.x * blockDim.x + threadIdx.x) * 8;
  unsigned short o[8];
#pragma unroll
  for (int j = 0; j < 8; ++j) o[j] = f2bf(in[i + j]);
  *(u16x8*)(out + i) = *(const u16x8*)o;
}

// ---------------------------------------------------------------------------
// biascat: out[0:4096] = fb2; out[4096+m] = (m<2048?wb1[m]:tb1[m-2048])
//                                + sum_j catT[m][j]*fb2[j]    (wave per row)
// ---------------------------------------------------------------------------
__global__ void biascat_kernel(const unsigned short* __restrict__ catT,
                               const float* __restrict__ fb2,
                               const float* __restrict__ wb1,
                               const float* __restrict__ tb1,
                               float* __restrict__ out) {
  int w    = blockIdx.x * 4 + (threadIdx.x >> 6);   // 0..8191
  int lane = threadIdx.x & 63;
  if (w < 4096) { if (lane == 0) out[w] = fb2[w]; return; }
  int m = w - 4096;
  const unsigned short* row = catT + (size_t)m * 4096;
  float s = 0.f;
  for (int k = lane * 8; k < 4096; k += 512) {
    u16x8 v = *(const u16x8*)(row + k);
#pragma unroll
    for (int j = 0; j < 8; ++j) s += bf2f(v[j]) * fb2[k + j];
  }
#pragma unroll
  for (int off = 32; off; off >>= 1) s += __shfl_down(s, off);
  if (lane == 0) out[w] = s + (m < 2048 ? wb1[m] : tb1[m - 2048]);
}

// ---------------------------------------------------------------------------
// 128x128 bf16 MFMA GEMM (r1-proven structure, 2 blocks/CU) for the weight
// product W2catT = (fw2 @ [ww1|tw1])^T.  C[m][n] = sum_k A[m,k]*BT[n,k],
// no bias, no relu, bf16 out.
// ---------------------------------------------------------------------------
__global__ __launch_bounds__(256, 2)
void gemm128_kernel(const unsigned short* __restrict__ A,
                    const unsigned short* __restrict__ BT,
                    unsigned short* __restrict__ outB,
                    int N, int K) {
  constexpr int BK = 64;
  __shared__ unsigned short As[128 * BK];
  __shared__ unsigned short Bs[128 * BK];

  const int bm = blockIdx.x, bn = blockIdx.y;
  const int tid = threadIdx.x;
  const int wid = tid >> 6, lane = tid & 63;
  const int wr = wid >> 1, wc = wid & 1;
  const int lr = lane & 15, lg = lane >> 4;

  f32x4 acc[4][4];
#pragma unroll
  for (int m = 0; m < 4; ++m)
#pragma unroll
    for (int n = 0; n < 4; ++n) acc[m][n] = (f32x4)0.f;

  const int srow = wid * 32 + (lane >> 3);
  const int scol = (lane & 7) * 8;
  const unsigned short* Ag = A  + (size_t)(bm * 128 + srow) * K + scol;
  const unsigned short* Bg = BT + (size_t)(bn * 128 + srow) * K + scol;

  for (int kt = 0; kt < K; kt += BK) {
#pragma unroll
    for (int i = 0; i < 4; ++i) {
      __builtin_amdgcn_global_load_lds(
          (const __attribute__((address_space(1))) unsigned int*)(Ag + (size_t)i * 8 * K + kt),
          (__attribute__((address_space(3))) unsigned int*)&As[wid * 2048 + i * 512],
          16, 0, 0);
      __builtin_amdgcn_global_load_lds(
          (const __attribute__((address_space(1))) unsigned int*)(Bg + (size_t)i * 8 * K + kt),
          (__attribute__((address_space(3))) unsigned int*)&Bs[wid * 2048 + i * 512],
          16, 0, 0);
    }
    __syncthreads();
#pragma unroll
    for (int kk = 0; kk < 2; ++kk) {
      u16x8 af[4], bf[4];
#pragma unroll
      for (int m = 0; m < 4; ++m)
        af[m] = *(const u16x8*)&As[(wr * 64 + m * 16 + lr) * BK + kk * 32 + lg * 8];
#pragma unroll
      for (int n = 0; n < 4; ++n)
        bf[n] = *(const u16x8*)&Bs[(wc * 64 + n * 16 + lr) * BK + kk * 32 + lg * 8];
#pragma unroll
      for (int m = 0; m < 4; ++m)
#pragma unroll
        for (int n = 0; n < 4; ++n)
          acc[m][n] = __builtin_amdgcn_mfma_f32_16x16x32_bf16(
              __builtin_bit_cast(bf16x8, af[m]),
              __builtin_bit_cast(bf16x8, bf[n]),
              acc[m][n], 0, 0, 0);
    }
    __syncthreads();
  }

  const int rowBase = bm * 128 + wr * 64 + lg * 4;
  const int colBase = bn * 128 + wc * 64 + lr;
#pragma unroll
  for (int n = 0; n < 4; ++n) {
    int col = colBase + n * 16;
#pragma unroll
    for (int m = 0; m < 4; ++m) {
      int row = rowBase + m * 16;
#pragma unroll
      for (int j = 0; j < 4; ++j)
        outB[(size_t)(row + j) * N + col] = f2bf(acc[m][n][j]);
    }
  }
}

// ---------------------------------------------------------------------------
// 256x256 bf16 MFMA GEMM, K32 ring of 4 (128KB), 8 waves, r4 schedule
// (counted vmcnt + counted lgkm clusters, T1/T2/T5). Split epilogue:
//   bn <  nFtiles : C+bias -> f32 outF (no relu), row stride NF
//   bn >= nFtiles : relu(C+bias) -> bf16 outB at col-4096, row stride NB
// A row stride = lda.  C[m][n] = sum_k A[m*lda+k]*BT[n*K+k] + bias[n].
// ---------------------------------------------------------------------------
#define GLL(gp, lp)                                                            \
  __builtin_amdgcn_global_load_lds(                                            \
      (const __attribute__((address_space(1))) unsigned int*)(gp),             \
      (__attribute__((address_space(3))) unsigned int*)(lp), 16, 0, 0)

#define DSREAD(dst, addr)                                                      \
  asm volatile("ds_read_b128 %0, %1" : "=v"(dst) : "v"(addr))

#define LGKM(n)                                                                \
  do { asm volatile("s_waitcnt lgkmcnt(" #n ")" ::: "memory");                 \
       __builtin_amdgcn_sched_barrier(0); } while (0)

#define FENCE() asm volatile("" ::: "memory")

extern __shared__ char lds_raw[];

__global__ __launch_bounds__(512)
void gemm256_kernel(const unsigned short* __restrict__ A,
                    const unsigned short* __restrict__ BT,
                    const float* __restrict__ bias,
                    float* __restrict__ outF,
                    unsigned short* __restrict__ outB,
                    int lda, int K, int NF, int NB, int nFtiles, int gmx) {
  const int NT = K >> 5;                      // K32 tiles

  // T1: bijective XCD swizzle, bm fastest
  const int nwg = gridDim.x;
  const int q = nwg >> 3, r = nwg & 7;
  const int xcd = blockIdx.x & 7, lid = blockIdx.x >> 3;
  const int wg2 = (xcd < r ? xcd * (q + 1) : r * (q + 1) + (xcd - r) * q) + lid;
  const int bm = wg2 % gmx, bn = wg2 / gmx;

  const int tid  = threadIdx.x;
  const int wid  = tid >> 6, lane = tid & 63;
  const int wr   = wid >> 2, wc = wid & 3;          // 2 x 4 waves
  const int lr   = lane & 15, lg = lane >> 4;

  // ---- staging (pre-swizzled global source, linear LDS dest) ----
  const int srow = tid >> 2;
  const int scol = ((tid & 3) ^ ((tid >> 3) & 3)) * 8;   // elems
  const unsigned short* agp0 = A  + (size_t)(bm * 256 + srow) * lda + scol;
  const unsigned short* agp1 = agp0 + (size_t)128 * lda;
  const unsigned short* bgp0 = BT + (size_t)(bn * 256 + srow) * K + scol;
  const unsigned short* bgp1 = bgp0 + (size_t)128 * K;

  // ---- read-side swizzled fragment offsets (0 bank conflicts) ----
  const int chunk = lg ^ ((lr >> 1) & 3);
  const unsigned ldsbase = (unsigned)(uintptr_t)&lds_raw[0];
  const unsigned aoff = (unsigned)((wr * 128 + lr) * 64 + chunk * 16);
  const unsigned boff = (unsigned)(16384 + (wc * 64 + lr) * 64 + chunk * 16);

  f32x4 acc[8][4];
#pragma unroll
  for (int m = 0; m < 8; ++m)
#pragma unroll
    for (int n = 0; n < 4; ++n) acc[m][n] = (f32x4)0.f;

#define STAGE_A(tt) do { unsigned so = (unsigned)(((tt) & 3) << 15);           \
    GLL(agp0 + (size_t)(tt) * 32, lds_raw + so + tid * 16);                    \
    GLL(agp1 + (size_t)(tt) * 32, lds_raw + so + 8192 + tid * 16); } while (0)
#define STAGE_B(tt) do { unsigned so = (unsigned)(((tt) & 3) << 15);           \
    GLL(bgp0 + (size_t)(tt) * 32, lds_raw + so + 16384 + tid * 16);            \
    GLL(bgp1 + (size_t)(tt) * 32, lds_raw + so + 24576 + tid * 16); } while (0)

  STAGE_A(0); STAGE_B(0); STAGE_A(1); STAGE_B(1); STAGE_A(2); STAGE_B(2);

  for (int t = 0; t < NT; ++t) {
    const int rem = NT - 1 - t;
    if (rem >= 2)      asm volatile("s_waitcnt vmcnt(8)" ::: "memory");
    else if (rem == 1) asm volatile("s_waitcnt vmcnt(4)" ::: "memory");
    else               asm volatile("s_waitcnt vmcnt(0)" ::: "memory");
    FENCE(); __builtin_amdgcn_s_barrier(); FENCE();
    __builtin_amdgcn_sched_barrier(0);

    const unsigned sbase = ldsbase + (unsigned)((t & 3) << 15);

    u16x8 b[4], a[8];
    DSREAD(b[0], sbase + boff);
    DSREAD(b[1], sbase + boff + 1024);
    DSREAD(b[2], sbase + boff + 2048);
    DSREAD(b[3], sbase + boff + 3072);
    DSREAD(a[0], sbase + aoff);
    DSREAD(a[1], sbase + aoff + 1024);
    DSREAD(a[2], sbase + aoff + 2048);
    DSREAD(a[3], sbase + aoff + 3072);
    DSREAD(a[4], sbase + aoff + 4096);
    DSREAD(a[5], sbase + aoff + 5120);
    DSREAD(a[6], sbase + aoff + 6144);
    DSREAD(a[7], sbase + aoff + 7168);
    if (t + 3 < NT) { STAGE_A(t + 3); STAGE_B(t + 3); }

    __builtin_amdgcn_s_setprio(1);
#define CLUSTER(m, g)                                                          \
    LGKM(g);                                                                   \
    acc[m][0] = __builtin_amdgcn_mfma_f32_16x16x32_bf16(                       \
        __builtin_bit_cast(bf16x8, a[m]), __builtin_bit_cast(bf16x8, b[0]),    \
        acc[m][0], 0, 0, 0);                                                   \
    acc[m][1] = __builtin_amdgcn_mfma_f32_16x16x32_bf16(                       \
        __builtin_bit_cast(bf16x8, a[m]), __builtin_bit_cast(bf16x8, b[1]),    \
        acc[m][1], 0, 0, 0);                                                   \
    acc[m][2] = __builtin_amdgcn_mfma_f32_16x16x32_bf16(                       \
        __builtin_bit_cast(bf16x8, a[m]), __builtin_bit_cast(bf16x8, b[2]),    \
        acc[m][2], 0, 0, 0);                                                   \
    acc[m][3] = __builtin_amdgcn_mfma_f32_16x16x32_bf16(                       \
        __builtin_bit_cast(bf16x8, a[m]), __builtin_bit_cast(bf16x8, b[3]),    \
        acc[m][3], 0, 0, 0)

    CLUSTER(0, 7);
    CLUSTER(1, 6);
    CLUSTER(2, 5);
    CLUSTER(3, 4);
    CLUSTER(4, 3);
    CLUSTER(5, 2);
    CLUSTER(6, 1);
    CLUSTER(7, 0);
#undef CLUSTER
    __builtin_amdgcn_s_setprio(0);
    __builtin_amdgcn_sched_barrier(0);
  }
#undef STAGE_A
#undef STAGE_B

  const int rowBase = bm * 256 + wr * 128 + lg * 4;
  const int colBase = bn * 256 + wc * 64 + lr;
  if (bn < nFtiles) {
#pragma unroll
    for (int n = 0; n < 4; ++n) {
      int col = colBase + n * 16;
      float bv = bias[col];
#pragma unroll
      for (int m = 0; m < 8; ++m) {
        int row = rowBase + m * 16;
#pragma unroll
        for (int j = 0; j < 4; ++j)
          outF[(size_t)(row + j) * NF + col] = acc[m][n][j] + bv;
      }
    }
  } else {
    const int colB = colBase - nFtiles * 256;
#pragma unroll
    for (int n = 0; n < 4; ++n) {
      int col = colB + n * 16;
      float bv = bias[colBase + n * 16];
#pragma unroll
      for (int m = 0; m < 8; ++m) {
        int row = rowBase + m * 16;
#pragma unroll
        for (int j = 0; j < 4; ++j)
          outB[(size_t)(row + j) * NB + col] = f2bf(fmaxf(acc[m][n][j] + bv, 0.f));
      }
    }
  }
}

// ---------------------------------------------------------------------------
// GEMV head: out[m] = sum_k A[m*lda+k]*w[k] + b.  One wave per row.
// ---------------------------------------------------------------------------
__global__ void gemv_kernel(const unsigned short* __restrict__ Abf,
                            const float* __restrict__ wvec,
                            const float* __restrict__ bias,
                            float* __restrict__ out, int K, int lda) {
  int row  = blockIdx.x * 4 + (threadIdx.x >> 6);
  int lane = threadIdx.x & 63;
  const unsigned short* ap = Abf + (size_t)row * lda;
  float s = 0.f;
  for (int k = lane * 8; k < K; k += 512) {
    u16x8 v = *(const u16x8*)(ap + k);
#pragma unroll
    for (int j = 0; j < 8; ++j) s += bf2f(v[j]) * wvec[k + j];
  }
#pragma unroll
  for (int off = 32; off; off >>= 1) s += __shfl_down(s, off);
  if (lane == 0) out[row] = s + bias[0];
}

// ---------------------------------------------------------------------------
extern "C" void kernel_launch(void* const* d_in, const int* in_sizes, int n_in,
                              void* d_out, int out_size, void* d_ws, size_t ws_size,
                              hipStream_t stream) {
  const float* x     = (const float*)d_in[0];
  const float* field = (const float*)d_in[1];
  const float* fw1   = (const float*)d_in[2];
  const float* fb1   = (const float*)d_in[3];
  const float* fw2   = (const float*)d_in[4];
  const float* fb2   = (const float*)d_in[5];
  const float* ww1   = (const float*)d_in[6];
  const float* wb1   = (const float*)d_in[7];
  const float* ww2   = (const float*)d_in[8];
  const float* wb2   = (const float*)d_in[9];
  const float* ww3   = (const float*)d_in[10];
  const float* wb3   = (const float*)d_in[11];
  const float* tw1   = (const float*)d_in[12];
  const float* tb1   = (const float*)d_in[13];
  const float* tw2   = (const float*)d_in[14];
  const float* tb2   = (const float*)d_in[15];

  const int M = 16384;
  float* outF    = (float*)d_out;                  // field_output [16384,4096]
  float* outWil  = outF + (size_t)M * 4096;
  float* outTop  = outWil + M;
  float* outPlaq = outTop + M;

  char* ws = (char*)d_ws;
  const size_t MB = 1048576;
  unsigned short* hbuf    = (unsigned short*)(ws);              // [16384,2048] 64MB
  unsigned short* catbuf  = (unsigned short*)(ws + 64  * MB);   // [16384,4096] 128MB (w1|t)
  unsigned short* catT    = (unsigned short*)(ws + 192 * MB);   // [4096,4096]  32MB (dead after GEMM_W)
  unsigned short* w2buf   = (unsigned short*)(ws + 192 * MB);   // [16384,1024] 32MB (reuses catT)
  unsigned short* fw2T    = (unsigned short*)(ws + 224 * MB);   // [4096,2048]  16MB  \ contiguous =
  unsigned short* W2catT  = (unsigned short*)(ws + 240 * MB);   // [4096,2048]  16MB  / BTcat [8192,2048]
  unsigned short* BTcat   = fw2T;
  unsigned short* fw2bf   = (unsigned short*)(ws + 256 * MB);   // [2048,4096]  16MB
  unsigned short* ww2T    = (unsigned short*)(ws + 272 * MB);   // [1024,2048]  4MB
  float*          biascat = (float*)(ws + 276 * MB);            // [8192] 32KB

  const int SMEM = 131072;
  (void)hipFuncSetAttribute((const void*)gemm256_kernel,
                            hipFuncAttributeMaxDynamicSharedMemorySize, SMEM);

  // independent prep
  hipLaunchKernelGGL(plaq_kernel, dim3(1), dim3(64), 0, stream, x, field, outPlaq);
  hipLaunchKernelGGL(fc1_kernel, dim3(16384), dim3(256), 0, stream, x, fw1, fb1, hbuf);
  hipLaunchKernelGGL(transpose_bf16_kernel, dim3(128, 64), dim3(32, 8), 0, stream,
                     fw2, fw2T, 2048, 4096);
  hipLaunchKernelGGL(cast_bf16_kernel, dim3(4096), dim3(256), 0, stream, fw2, fw2bf);
  hipLaunchKernelGGL(transpose_bf16_kernel, dim3(64, 128), dim3(32, 8), 0, stream,
                     ww1, catT, 4096, 2048);
  hipLaunchKernelGGL(transpose_bf16_kernel, dim3(64, 128), dim3(32, 8), 0, stream,
                     tw1, catT + (size_t)2048 * 4096, 4096, 2048);
  hipLaunchKernelGGL(transpose_bf16_kernel, dim3(32, 64), dim3(32, 8), 0, stream,
                     ww2, ww2T, 2048, 1024);
  hipLaunchKernelGGL(biascat_kernel, dim3(2048), dim3(256), 0, stream,
                     catT, fb2, wb1, tb1, biascat);

  // W2catT[n][k] = sum_j catT[n][j] * fw2bf[k][j]   (M=4096, N=2048, K=4096)
  hipLaunchKernelGGL(gemm128_kernel, dim3(32, 16), dim3(256), 0, stream,
                     catT, fw2bf, W2catT, 2048, 4096);

  // fused: C = h @ [fw2 | W2cat] + biascat   (M=16384, N=8192, K=2048)
  //   bn<16: field_output f32 -> outF;  bn>=16: relu bf16 -> catbuf
  hipLaunchKernelGGL(gemm256_kernel, dim3(64 * 32), dim3(512), SMEM, stream,
                     hbuf, BTcat, biascat, outF, catbuf,
                     2048, 2048, 4096, 4096, 16, 64);

  // w2 = relu(w1 @ ww2 + wb2)   (A = catbuf cols 0..2047, lda 4096)
  hipLaunchKernelGGL(gemm256_kernel, dim3(64 * 4), dim3(512), SMEM, stream,
                     catbuf, ww2T, wb2, (float*)nullptr, w2buf,
                     4096, 2048, 0, 1024, 0, 64);

  // heads
  hipLaunchKernelGGL(gemv_kernel, dim3(4096), dim3(256), 0, stream,
                     w2buf, ww3, wb3, outWil, 1024, 1024);
  hipLaunchKernelGGL(gemv_kernel, dim3(4096), dim3(256), 0, stream,
                     catbuf + 2048, tw2, tb2, outTop, 2048, 4096);

  (void)in_sizes; (void)n_in; (void)out_size; (void)ws_size;
}